// Round 4
// baseline (121.441 us; speedup 1.0000x reference)
//
#include <hip/hip_runtime.h>

#define Hn 768
#define Bn 16
#define Sn 512
#define En 32
#define Vn 50265

// ---------------- Layer 1: o1 = g1*inst + (1-g1)*sent, g1 = sigmoid(inst@W1_1 + sent@W1_2)
// Only the one event row per batch that the LM head observes is computed.
// Block: 256 threads = 4 waves; wave ks handles k in [ks*192, ks*192+192) for 64 j's.
__global__ __launch_bounds__(256) void gate_layer1(
    const int* __restrict__ batch_arg, const int* __restrict__ event_pos,
    const int* __restrict__ mask_indices, const float* __restrict__ sent_emb,
    const float* __restrict__ emb_table, const float* __restrict__ W1_1,
    const float* __restrict__ W1_2, float* __restrict__ o1_out)
{
    const int b  = blockIdx.x;
    const int j0 = threadIdx.x & 63;
    const int ks = threadIdx.x >> 6;           // wave-uniform
    const int j  = blockIdx.y * 64 + j0;

    const int mask = mask_indices[b];
    int estar = -1;
    #pragma unroll
    for (int e = 0; e < En; ++e)
        if (event_pos[b * En + e] == mask && estar < 0) estar = e;
    const int tok = batch_arg[b * Sn + mask];

    __shared__ __align__(16) float s_inst[Hn];
    __shared__ __align__(16) float s_sent[Hn];
    for (int t = threadIdx.x; t < Hn; t += 256) {
        s_inst[t] = emb_table[(size_t)tok * Hn + t];
        s_sent[t] = (estar >= 0) ? sent_emb[((size_t)b * En + estar) * Hn + t] : 0.f;
    }
    __syncthreads();

    float a0 = 0.f, a1 = 0.f, c0 = 0.f, c1 = 0.f;
    const float* __restrict__ w1 = W1_1 + (size_t)ks * 192 * Hn + j;
    const float* __restrict__ w2 = W1_2 + (size_t)ks * 192 * Hn + j;
    const float4* __restrict__ si = (const float4*)(s_inst + ks * 192);
    const float4* __restrict__ ss = (const float4*)(s_sent + ks * 192);
    #pragma unroll 4
    for (int k4 = 0; k4 < 48; ++k4) {
        const float4 iv = si[k4];                 // ds_read_b128 broadcast
        const float4 sv = ss[k4];
        const float* __restrict__ wa = w1 + (size_t)k4 * 4 * Hn;
        const float* __restrict__ wb = w2 + (size_t)k4 * 4 * Hn;
        a0 = fmaf(iv.x, wa[0],          a0);
        a1 = fmaf(iv.y, wa[Hn],         a1);
        a0 = fmaf(iv.z, wa[2 * Hn],     a0);
        a1 = fmaf(iv.w, wa[3 * Hn],     a1);
        c0 = fmaf(sv.x, wb[0],          c0);
        c1 = fmaf(sv.y, wb[Hn],         c1);
        c0 = fmaf(sv.z, wb[2 * Hn],     c0);
        c1 = fmaf(sv.w, wb[3 * Hn],     c1);
    }

    __shared__ float r_a[4][64];
    __shared__ float r_c[4][64];
    r_a[ks][j0] = a0 + a1; r_c[ks][j0] = c0 + c1;
    __syncthreads();
    if (ks == 0) {
        const float A = r_a[0][j0] + r_a[1][j0] + r_a[2][j0] + r_a[3][j0];
        const float C = r_c[0][j0] + r_c[1][j0] + r_c[2][j0] + r_c[3][j0];
        const float g = 1.f / (1.f + expf(-(A + C)));
        o1_out[b * Hn + j] = g * s_inst[j] + (1.f - g) * s_sent[j];
    }
}

// ---------------- Layer 2: o2 = g2*o1 + (1-g2)*typ, written TRANSPOSED as me_t[k][b]
__global__ __launch_bounds__(256) void gate_layer2(
    const int* __restrict__ batch_arg, const int* __restrict__ event_pos,
    const int* __restrict__ mask_indices, const float* __restrict__ type_emb,
    const float* __restrict__ emb_table, const float* __restrict__ W2_1,
    const float* __restrict__ W2_2, const float* __restrict__ o1_in,
    float* __restrict__ me_t)
{
    const int b  = blockIdx.x;
    const int j0 = threadIdx.x & 63;
    const int ks = threadIdx.x >> 6;
    const int j  = blockIdx.y * 64 + j0;

    const int mask = mask_indices[b];
    int estar = -1;
    #pragma unroll
    for (int e = 0; e < En; ++e)
        if (event_pos[b * En + e] == mask && estar < 0) estar = e;
    const int tok = batch_arg[b * Sn + mask];

    __shared__ __align__(16) float s_o1[Hn];
    __shared__ __align__(16) float s_typ[Hn];
    for (int t = threadIdx.x; t < Hn; t += 256) {
        s_o1[t]  = o1_in[b * Hn + t];
        s_typ[t] = type_emb[((size_t)b * Sn + mask) * Hn + t];
    }
    __syncthreads();

    float a0 = 0.f, a1 = 0.f, c0 = 0.f, c1 = 0.f;
    const float* __restrict__ w1 = W2_1 + (size_t)ks * 192 * Hn + j;
    const float* __restrict__ w2 = W2_2 + (size_t)ks * 192 * Hn + j;
    const float4* __restrict__ so = (const float4*)(s_o1  + ks * 192);
    const float4* __restrict__ st = (const float4*)(s_typ + ks * 192);
    #pragma unroll 4
    for (int k4 = 0; k4 < 48; ++k4) {
        const float4 ov = so[k4];
        const float4 tv = st[k4];
        const float* __restrict__ wa = w1 + (size_t)k4 * 4 * Hn;
        const float* __restrict__ wb = w2 + (size_t)k4 * 4 * Hn;
        a0 = fmaf(ov.x, wa[0],          a0);
        a1 = fmaf(ov.y, wa[Hn],         a1);
        a0 = fmaf(ov.z, wa[2 * Hn],     a0);
        a1 = fmaf(ov.w, wa[3 * Hn],     a1);
        c0 = fmaf(tv.x, wb[0],          c0);
        c1 = fmaf(tv.y, wb[Hn],         c1);
        c0 = fmaf(tv.z, wb[2 * Hn],     c0);
        c1 = fmaf(tv.w, wb[3 * Hn],     c1);
    }

    __shared__ float r_a[4][64];
    __shared__ float r_c[4][64];
    r_a[ks][j0] = a0 + a1; r_c[ks][j0] = c0 + c1;
    __syncthreads();
    if (ks == 0) {
        const float A = r_a[0][j0] + r_a[1][j0] + r_a[2][j0] + r_a[3][j0];
        const float C = r_c[0][j0] + r_c[1][j0] + r_c[2][j0] + r_c[3][j0];
        const float g = 1.f / (1.f + expf(-(A + C)));
        float o2 = g * s_o1[j] + (1.f - g) * s_typ[j];
        if (estar < 0) o2 = emb_table[(size_t)tok * Hn + j];  // mask row never updated
        me_t[j * Bn + b] = o2;
    }
}

// ---------------- LM head: out[b][v] = sum_k me_t[k][b]*lm_W[k][v] + lm_b[v]
// 786 blocks x 512 threads; 8 waves split K (96 each) for the same 64 v's.
// me operand: 4x float4 broadcast loads per k (5 VMEM instrs/k vs 16 FMA) ->
// VALU-bound inner loop. Cross-wave reduce via 32 KB LDS; bias fused.
__global__ __launch_bounds__(512) void lm_head(
    const float* __restrict__ me_t, const float* __restrict__ lm_W,
    const float* __restrict__ lm_b, float* __restrict__ out)
{
    const int tid  = threadIdx.x;
    const int lane = tid & 63;
    const int w    = tid >> 6;                    // 0..7
    const int v    = blockIdx.x * 64 + lane;
    const int vc   = (v < Vn) ? v : (Vn - 1);     // clamp: garbage lanes never stored

    const int kb = w * 96;
    float4 a0 = {0.f, 0.f, 0.f, 0.f};
    float4 a1 = {0.f, 0.f, 0.f, 0.f};
    float4 a2 = {0.f, 0.f, 0.f, 0.f};
    float4 a3 = {0.f, 0.f, 0.f, 0.f};

    const float*  __restrict__ wp = lm_W + (size_t)kb * Vn + vc;
    const float4* __restrict__ mp = (const float4*)(me_t + kb * Bn);

    #pragma unroll 4
    for (int k = 0; k < 96; ++k) {
        const float wv = wp[(size_t)k * Vn];      // coalesced 256B/wave
        const float4 m0 = mp[k * 4 + 0];          // broadcast, one L1 line
        const float4 m1 = mp[k * 4 + 1];
        const float4 m2 = mp[k * 4 + 2];
        const float4 m3 = mp[k * 4 + 3];
        a0.x = fmaf(m0.x, wv, a0.x); a0.y = fmaf(m0.y, wv, a0.y);
        a0.z = fmaf(m0.z, wv, a0.z); a0.w = fmaf(m0.w, wv, a0.w);
        a1.x = fmaf(m1.x, wv, a1.x); a1.y = fmaf(m1.y, wv, a1.y);
        a1.z = fmaf(m1.z, wv, a1.z); a1.w = fmaf(m1.w, wv, a1.w);
        a2.x = fmaf(m2.x, wv, a2.x); a2.y = fmaf(m2.y, wv, a2.y);
        a2.z = fmaf(m2.z, wv, a2.z); a2.w = fmaf(m2.w, wv, a2.w);
        a3.x = fmaf(m3.x, wv, a3.x); a3.y = fmaf(m3.y, wv, a3.y);
        a3.z = fmaf(m3.z, wv, a3.z); a3.w = fmaf(m3.w, wv, a3.w);
    }

    __shared__ float red[8 * Bn * 64];            // 32 KB
    const float accf[Bn] = {a0.x, a0.y, a0.z, a0.w, a1.x, a1.y, a1.z, a1.w,
                            a2.x, a2.y, a2.z, a2.w, a3.x, a3.y, a3.z, a3.w};
    #pragma unroll
    for (int b = 0; b < Bn; ++b)
        red[(w * Bn + b) * 64 + lane] = accf[b];
    __syncthreads();

    #pragma unroll
    for (int p0 = 0; p0 < 2; ++p0) {
        const int p  = p0 * 512 + tid;            // 0..1023 = 16 b x 64 v
        const int b  = p >> 6;
        const int l  = p & 63;
        const int vv = blockIdx.x * 64 + l;
        if (vv < Vn) {
            float s = 0.f;
            #pragma unroll
            for (int ww = 0; ww < 8; ++ww) s += red[(ww * Bn + b) * 64 + l];
            out[(size_t)b * Vn + vv] = s + lm_b[vv];
        }
    }
}

extern "C" void kernel_launch(void* const* d_in, const int* in_sizes, int n_in,
                              void* d_out, int out_size, void* d_ws, size_t ws_size,
                              hipStream_t stream) {
    const int*   batch_arg    = (const int*)  d_in[0];
    const int*   event_pos    = (const int*)  d_in[1];
    const int*   mask_indices = (const int*)  d_in[2];
    const float* sent_emb     = (const float*)d_in[3];
    const float* type_emb     = (const float*)d_in[4];
    const float* emb_table    = (const float*)d_in[5];
    const float* W1_1         = (const float*)d_in[6];
    const float* W1_2         = (const float*)d_in[7];
    const float* W2_1         = (const float*)d_in[8];
    const float* W2_2         = (const float*)d_in[9];
    const float* lm_W         = (const float*)d_in[10];
    const float* lm_b         = (const float*)d_in[11];
    float* out = (float*)d_out;

    float* o1_ws = (float*)d_ws;                 // Bn*Hn floats
    float* me_t  = o1_ws + (size_t)Bn * Hn;      // Hn*Bn floats (16B aligned)

    dim3 g12(Bn, Hn / 64);
    gate_layer1<<<g12, 256, 0, stream>>>(batch_arg, event_pos, mask_indices,
                                         sent_emb, emb_table, W1_1, W1_2, o1_ws);
    gate_layer2<<<g12, 256, 0, stream>>>(batch_arg, event_pos, mask_indices,
                                         type_emb, emb_table, W2_1, W2_2, o1_ws, me_t);

    lm_head<<<(Vn + 63) / 64, 512, 0, stream>>>(me_t, lm_W, lm_b, out);
}

// Round 6
// 109.533 us; speedup vs baseline: 1.1087x; 1.1087x over previous
//
#include <hip/hip_runtime.h>

#define Hn 768
#define Bn 16
#define Sn 512
#define En 32
#define Vn 50265

#define WPB 8           // waves per lm_head block
#define KPW (Hn / WPB)  // 96 k per wave
#define VPB 128         // v per lm_head block
#define CH  8           // wv prefetch depth (k's per chunk)

// ---------------- Layer 1: o1 = g1*inst + (1-g1)*sent, g1 = sigmoid(inst@W1_1 + sent@W1_2)
__global__ __launch_bounds__(256) void gate_layer1(
    const int* __restrict__ batch_arg, const int* __restrict__ event_pos,
    const int* __restrict__ mask_indices, const float* __restrict__ sent_emb,
    const float* __restrict__ emb_table, const float* __restrict__ W1_1,
    const float* __restrict__ W1_2, float* __restrict__ o1_out)
{
    const int b  = blockIdx.x;
    const int j0 = threadIdx.x & 63;
    const int ks = threadIdx.x >> 6;           // wave-uniform
    const int j  = blockIdx.y * 64 + j0;

    const int mask = mask_indices[b];
    int estar = -1;
    #pragma unroll
    for (int e = 0; e < En; ++e)
        if (event_pos[b * En + e] == mask && estar < 0) estar = e;
    const int tok = batch_arg[b * Sn + mask];

    __shared__ __align__(16) float s_inst[Hn];
    __shared__ __align__(16) float s_sent[Hn];
    for (int t = threadIdx.x; t < Hn; t += 256) {
        s_inst[t] = emb_table[(size_t)tok * Hn + t];
        s_sent[t] = (estar >= 0) ? sent_emb[((size_t)b * En + estar) * Hn + t] : 0.f;
    }
    __syncthreads();

    float a0 = 0.f, a1 = 0.f, c0 = 0.f, c1 = 0.f;
    const float* __restrict__ w1 = W1_1 + (size_t)ks * 192 * Hn + j;
    const float* __restrict__ w2 = W1_2 + (size_t)ks * 192 * Hn + j;
    const float4* __restrict__ si = (const float4*)(s_inst + ks * 192);
    const float4* __restrict__ ss = (const float4*)(s_sent + ks * 192);
    #pragma unroll 4
    for (int k4 = 0; k4 < 48; ++k4) {
        const float4 iv = si[k4];
        const float4 sv = ss[k4];
        const float* __restrict__ wa = w1 + (size_t)k4 * 4 * Hn;
        const float* __restrict__ wb = w2 + (size_t)k4 * 4 * Hn;
        a0 = fmaf(iv.x, wa[0],      a0);
        a1 = fmaf(iv.y, wa[Hn],     a1);
        a0 = fmaf(iv.z, wa[2 * Hn], a0);
        a1 = fmaf(iv.w, wa[3 * Hn], a1);
        c0 = fmaf(sv.x, wb[0],      c0);
        c1 = fmaf(sv.y, wb[Hn],     c1);
        c0 = fmaf(sv.z, wb[2 * Hn], c0);
        c1 = fmaf(sv.w, wb[3 * Hn], c1);
    }

    __shared__ float r_a[4][64];
    __shared__ float r_c[4][64];
    r_a[ks][j0] = a0 + a1; r_c[ks][j0] = c0 + c1;
    __syncthreads();
    if (ks == 0) {
        const float A = r_a[0][j0] + r_a[1][j0] + r_a[2][j0] + r_a[3][j0];
        const float C = r_c[0][j0] + r_c[1][j0] + r_c[2][j0] + r_c[3][j0];
        const float g = 1.f / (1.f + expf(-(A + C)));
        o1_out[b * Hn + j] = g * s_inst[j] + (1.f - g) * s_sent[j];
    }
}

// ---------------- Layer 2: o2 = g2*o1 + (1-g2)*typ, written TRANSPOSED as me_t[k][b]
__global__ __launch_bounds__(256) void gate_layer2(
    const int* __restrict__ batch_arg, const int* __restrict__ event_pos,
    const int* __restrict__ mask_indices, const float* __restrict__ type_emb,
    const float* __restrict__ emb_table, const float* __restrict__ W2_1,
    const float* __restrict__ W2_2, const float* __restrict__ o1_in,
    float* __restrict__ me_t)
{
    const int b  = blockIdx.x;
    const int j0 = threadIdx.x & 63;
    const int ks = threadIdx.x >> 6;
    const int j  = blockIdx.y * 64 + j0;

    const int mask = mask_indices[b];
    int estar = -1;
    #pragma unroll
    for (int e = 0; e < En; ++e)
        if (event_pos[b * En + e] == mask && estar < 0) estar = e;
    const int tok = batch_arg[b * Sn + mask];

    __shared__ __align__(16) float s_o1[Hn];
    __shared__ __align__(16) float s_typ[Hn];
    for (int t = threadIdx.x; t < Hn; t += 256) {
        s_o1[t]  = o1_in[b * Hn + t];
        s_typ[t] = type_emb[((size_t)b * Sn + mask) * Hn + t];
    }
    __syncthreads();

    float a0 = 0.f, a1 = 0.f, c0 = 0.f, c1 = 0.f;
    const float* __restrict__ w1 = W2_1 + (size_t)ks * 192 * Hn + j;
    const float* __restrict__ w2 = W2_2 + (size_t)ks * 192 * Hn + j;
    const float4* __restrict__ so = (const float4*)(s_o1  + ks * 192);
    const float4* __restrict__ st = (const float4*)(s_typ + ks * 192);
    #pragma unroll 4
    for (int k4 = 0; k4 < 48; ++k4) {
        const float4 ov = so[k4];
        const float4 tv = st[k4];
        const float* __restrict__ wa = w1 + (size_t)k4 * 4 * Hn;
        const float* __restrict__ wb = w2 + (size_t)k4 * 4 * Hn;
        a0 = fmaf(ov.x, wa[0],      a0);
        a1 = fmaf(ov.y, wa[Hn],     a1);
        a0 = fmaf(ov.z, wa[2 * Hn], a0);
        a1 = fmaf(ov.w, wa[3 * Hn], a1);
        c0 = fmaf(tv.x, wb[0],      c0);
        c1 = fmaf(tv.y, wb[Hn],     c1);
        c0 = fmaf(tv.z, wb[2 * Hn], c0);
        c1 = fmaf(tv.w, wb[3 * Hn], c1);
    }

    __shared__ float r_a[4][64];
    __shared__ float r_c[4][64];
    r_a[ks][j0] = a0 + a1; r_c[ks][j0] = c0 + c1;
    __syncthreads();
    if (ks == 0) {
        const float A = r_a[0][j0] + r_a[1][j0] + r_a[2][j0] + r_a[3][j0];
        const float C = r_c[0][j0] + r_c[1][j0] + r_c[2][j0] + r_c[3][j0];
        const float g = 1.f / (1.f + expf(-(A + C)));
        float o2 = g * s_o1[j] + (1.f - g) * s_typ[j];
        if (estar < 0) o2 = emb_table[(size_t)tok * Hn + j];  // mask row never updated
        me_t[j * Bn + b] = o2;
    }
}

// ---------------- LM head: out[b][v] = sum_k me_t[k][b]*lm_W[k][v] + lm_b[v]
// 393 blocks x 512 threads; 8 waves split K (96 each) over the block's 128 v's
// (2 v per thread via float2). Fast path prefetches 8 independent lm_W rows
// (4 KB of misses in flight per wave) BEFORE any use. Tail lanes (last block
// only) take a scalar path so valid v=50264 is computed correctly and OOB
// lanes never alias a valid red[] slot. 64 KB LDS cross-wave reduce; bias fused.
__global__ __launch_bounds__(512, 2) void lm_head(
    const float* __restrict__ me_t, const float* __restrict__ lm_W,
    const float* __restrict__ lm_b, float* __restrict__ out)
{
    const int tid  = threadIdx.x;
    const int lane = tid & 63;
    const int w    = tid >> 6;                        // 0..7
    const int v0   = blockIdx.x * VPB + lane * 2;     // two consecutive v's

    const int kb = w * KPW;
    float2 acc[Bn];
    #pragma unroll
    for (int i = 0; i < Bn; ++i) acc[i] = make_float2(0.f, 0.f);

    const float4* __restrict__ mp = (const float4*)(me_t + kb * Bn);

    if (v0 + 1 < Vn) {
        // ---- fast path: float2 weight stream with 8-deep prefetch
        const float* __restrict__ wp = lm_W + (size_t)kb * Vn + v0;
        for (int k0 = 0; k0 < KPW; k0 += CH) {
            float2 wb[CH];
            #pragma unroll
            for (int u = 0; u < CH; ++u)              // 8 independent misses in flight
                wb[u] = *(const float2*)(wp + (size_t)(k0 + u) * Vn);
            #pragma unroll
            for (int u = 0; u < CH; ++u) {
                const float2 wv = wb[u];
                const float4 m0 = mp[(k0 + u) * 4 + 0];   // broadcast, L2-resident
                const float4 m1 = mp[(k0 + u) * 4 + 1];
                const float4 m2 = mp[(k0 + u) * 4 + 2];
                const float4 m3 = mp[(k0 + u) * 4 + 3];
#define FMA8(q, mq)                                                          \
                acc[q*4+0].x = fmaf(mq.x, wv.x, acc[q*4+0].x);               \
                acc[q*4+0].y = fmaf(mq.x, wv.y, acc[q*4+0].y);               \
                acc[q*4+1].x = fmaf(mq.y, wv.x, acc[q*4+1].x);               \
                acc[q*4+1].y = fmaf(mq.y, wv.y, acc[q*4+1].y);               \
                acc[q*4+2].x = fmaf(mq.z, wv.x, acc[q*4+2].x);               \
                acc[q*4+2].y = fmaf(mq.z, wv.y, acc[q*4+2].y);               \
                acc[q*4+3].x = fmaf(mq.w, wv.x, acc[q*4+3].x);               \
                acc[q*4+3].y = fmaf(mq.w, wv.y, acc[q*4+3].y);
                FMA8(0, m0) FMA8(1, m1) FMA8(2, m2) FMA8(3, m3)
#undef FMA8
            }
        }
    } else {
        // ---- tail path (last block only): single valid v at most (v0 == Vn-1)
        const int vx = (v0 < Vn) ? v0 : (Vn - 1);     // OOB lanes: dummy, never read
        const float* __restrict__ wq = lm_W + (size_t)kb * Vn + vx;
        for (int k = 0; k < KPW; ++k) {
            const float wvx = wq[(size_t)k * Vn];
            const float4 m0 = mp[k * 4 + 0];
            const float4 m1 = mp[k * 4 + 1];
            const float4 m2 = mp[k * 4 + 2];
            const float4 m3 = mp[k * 4 + 3];
            acc[0].x  = fmaf(m0.x, wvx, acc[0].x);
            acc[1].x  = fmaf(m0.y, wvx, acc[1].x);
            acc[2].x  = fmaf(m0.z, wvx, acc[2].x);
            acc[3].x  = fmaf(m0.w, wvx, acc[3].x);
            acc[4].x  = fmaf(m1.x, wvx, acc[4].x);
            acc[5].x  = fmaf(m1.y, wvx, acc[5].x);
            acc[6].x  = fmaf(m1.z, wvx, acc[6].x);
            acc[7].x  = fmaf(m1.w, wvx, acc[7].x);
            acc[8].x  = fmaf(m2.x, wvx, acc[8].x);
            acc[9].x  = fmaf(m2.y, wvx, acc[9].x);
            acc[10].x = fmaf(m2.z, wvx, acc[10].x);
            acc[11].x = fmaf(m2.w, wvx, acc[11].x);
            acc[12].x = fmaf(m3.x, wvx, acc[12].x);
            acc[13].x = fmaf(m3.y, wvx, acc[13].x);
            acc[14].x = fmaf(m3.z, wvx, acc[14].x);
            acc[15].x = fmaf(m3.w, wvx, acc[15].x);
        }
    }

    __shared__ float red[WPB * Bn * VPB];             // 64 KB
    #pragma unroll
    for (int b = 0; b < Bn; ++b)
        *(float2*)&red[(w * Bn + b) * VPB + lane * 2] = acc[b];
    __syncthreads();

    #pragma unroll
    for (int p0 = 0; p0 < 4; ++p0) {
        const int p  = p0 * 512 + tid;                // 0..2047 = 16 b x 128 v
        const int b  = p >> 7;
        const int l  = p & 127;
        const int vv = blockIdx.x * VPB + l;
        if (vv < Vn) {
            float s = 0.f;
            #pragma unroll
            for (int ww = 0; ww < WPB; ++ww) s += red[(ww * Bn + b) * VPB + l];
            out[(size_t)b * Vn + vv] = s + lm_b[vv];
        }
    }
}

extern "C" void kernel_launch(void* const* d_in, const int* in_sizes, int n_in,
                              void* d_out, int out_size, void* d_ws, size_t ws_size,
                              hipStream_t stream) {
    const int*   batch_arg    = (const int*)  d_in[0];
    const int*   event_pos    = (const int*)  d_in[1];
    const int*   mask_indices = (const int*)  d_in[2];
    const float* sent_emb     = (const float*)d_in[3];
    const float* type_emb     = (const float*)d_in[4];
    const float* emb_table    = (const float*)d_in[5];
    const float* W1_1         = (const float*)d_in[6];
    const float* W1_2         = (const float*)d_in[7];
    const float* W2_1         = (const float*)d_in[8];
    const float* W2_2         = (const float*)d_in[9];
    const float* lm_W         = (const float*)d_in[10];
    const float* lm_b         = (const float*)d_in[11];
    float* out = (float*)d_out;

    float* o1_ws = (float*)d_ws;                 // Bn*Hn floats
    float* me_t  = o1_ws + (size_t)Bn * Hn;      // Hn*Bn floats (16B aligned)

    dim3 g12(Bn, Hn / 64);
    gate_layer1<<<g12, 256, 0, stream>>>(batch_arg, event_pos, mask_indices,
                                         sent_emb, emb_table, W1_1, W1_2, o1_ws);
    gate_layer2<<<g12, 256, 0, stream>>>(batch_arg, event_pos, mask_indices,
                                         type_emb, emb_table, W2_1, W2_2, o1_ws, me_t);

    lm_head<<<(Vn + VPB - 1) / VPB, 512, 0, stream>>>(me_t, lm_W, lm_b, out);
}

// Round 7
// 67.383 us; speedup vs baseline: 1.8022x; 1.6255x over previous
//
#include <hip/hip_runtime.h>

#define Hn 768
#define Bn 16
#define Sn 512
#define En 32
#define Vn 50265

#define WPB 8           // waves per lm_head block
#define KPW (Hn / WPB)  // 96 k per wave
#define VPB 128         // v per lm_head block
#define CH  8           // wv prefetch depth (k's per chunk)

// ---------------- Layer 1: o1 = g1*inst + (1-g1)*sent, g1 = sigmoid(inst@W1_1 + sent@W1_2)
__global__ __launch_bounds__(256) void gate_layer1(
    const int* __restrict__ batch_arg, const int* __restrict__ event_pos,
    const int* __restrict__ mask_indices, const float* __restrict__ sent_emb,
    const float* __restrict__ emb_table, const float* __restrict__ W1_1,
    const float* __restrict__ W1_2, float* __restrict__ o1_out)
{
    const int b  = blockIdx.x;
    const int j0 = threadIdx.x & 63;
    const int ks = threadIdx.x >> 6;           // wave-uniform
    const int j  = blockIdx.y * 64 + j0;

    const int mask = mask_indices[b];
    int estar = -1;
    #pragma unroll
    for (int e = 0; e < En; ++e)
        if (event_pos[b * En + e] == mask && estar < 0) estar = e;
    const int tok = batch_arg[b * Sn + mask];

    __shared__ __align__(16) float s_inst[Hn];
    __shared__ __align__(16) float s_sent[Hn];
    for (int t = threadIdx.x; t < Hn; t += 256) {
        s_inst[t] = emb_table[(size_t)tok * Hn + t];
        s_sent[t] = (estar >= 0) ? sent_emb[((size_t)b * En + estar) * Hn + t] : 0.f;
    }
    __syncthreads();

    float a0 = 0.f, a1 = 0.f, c0 = 0.f, c1 = 0.f;
    const float* __restrict__ w1 = W1_1 + (size_t)ks * 192 * Hn + j;
    const float* __restrict__ w2 = W1_2 + (size_t)ks * 192 * Hn + j;
    const float4* __restrict__ si = (const float4*)(s_inst + ks * 192);
    const float4* __restrict__ ss = (const float4*)(s_sent + ks * 192);
    #pragma unroll 4
    for (int k4 = 0; k4 < 48; ++k4) {
        const float4 iv = si[k4];
        const float4 sv = ss[k4];
        const float* __restrict__ wa = w1 + (size_t)k4 * 4 * Hn;
        const float* __restrict__ wb = w2 + (size_t)k4 * 4 * Hn;
        a0 = fmaf(iv.x, wa[0],      a0);
        a1 = fmaf(iv.y, wa[Hn],     a1);
        a0 = fmaf(iv.z, wa[2 * Hn], a0);
        a1 = fmaf(iv.w, wa[3 * Hn], a1);
        c0 = fmaf(sv.x, wb[0],      c0);
        c1 = fmaf(sv.y, wb[Hn],     c1);
        c0 = fmaf(sv.z, wb[2 * Hn], c0);
        c1 = fmaf(sv.w, wb[3 * Hn], c1);
    }

    __shared__ float r_a[4][64];
    __shared__ float r_c[4][64];
    r_a[ks][j0] = a0 + a1; r_c[ks][j0] = c0 + c1;
    __syncthreads();
    if (ks == 0) {
        const float A = r_a[0][j0] + r_a[1][j0] + r_a[2][j0] + r_a[3][j0];
        const float C = r_c[0][j0] + r_c[1][j0] + r_c[2][j0] + r_c[3][j0];
        const float g = 1.f / (1.f + expf(-(A + C)));
        o1_out[b * Hn + j] = g * s_inst[j] + (1.f - g) * s_sent[j];
    }
}

// ---------------- Layer 2: o2 = g2*o1 + (1-g2)*typ, written TRANSPOSED as me_t[k][b]
__global__ __launch_bounds__(256) void gate_layer2(
    const int* __restrict__ batch_arg, const int* __restrict__ event_pos,
    const int* __restrict__ mask_indices, const float* __restrict__ type_emb,
    const float* __restrict__ emb_table, const float* __restrict__ W2_1,
    const float* __restrict__ W2_2, const float* __restrict__ o1_in,
    float* __restrict__ me_t)
{
    const int b  = blockIdx.x;
    const int j0 = threadIdx.x & 63;
    const int ks = threadIdx.x >> 6;
    const int j  = blockIdx.y * 64 + j0;

    const int mask = mask_indices[b];
    int estar = -1;
    #pragma unroll
    for (int e = 0; e < En; ++e)
        if (event_pos[b * En + e] == mask && estar < 0) estar = e;
    const int tok = batch_arg[b * Sn + mask];

    __shared__ __align__(16) float s_o1[Hn];
    __shared__ __align__(16) float s_typ[Hn];
    for (int t = threadIdx.x; t < Hn; t += 256) {
        s_o1[t]  = o1_in[b * Hn + t];
        s_typ[t] = type_emb[((size_t)b * Sn + mask) * Hn + t];
    }
    __syncthreads();

    float a0 = 0.f, a1 = 0.f, c0 = 0.f, c1 = 0.f;
    const float* __restrict__ w1 = W2_1 + (size_t)ks * 192 * Hn + j;
    const float* __restrict__ w2 = W2_2 + (size_t)ks * 192 * Hn + j;
    const float4* __restrict__ so = (const float4*)(s_o1  + ks * 192);
    const float4* __restrict__ st = (const float4*)(s_typ + ks * 192);
    #pragma unroll 4
    for (int k4 = 0; k4 < 48; ++k4) {
        const float4 ov = so[k4];
        const float4 tv = st[k4];
        const float* __restrict__ wa = w1 + (size_t)k4 * 4 * Hn;
        const float* __restrict__ wb = w2 + (size_t)k4 * 4 * Hn;
        a0 = fmaf(ov.x, wa[0],      a0);
        a1 = fmaf(ov.y, wa[Hn],     a1);
        a0 = fmaf(ov.z, wa[2 * Hn], a0);
        a1 = fmaf(ov.w, wa[3 * Hn], a1);
        c0 = fmaf(tv.x, wb[0],      c0);
        c1 = fmaf(tv.y, wb[Hn],     c1);
        c0 = fmaf(tv.z, wb[2 * Hn], c0);
        c1 = fmaf(tv.w, wb[3 * Hn], c1);
    }

    __shared__ float r_a[4][64];
    __shared__ float r_c[4][64];
    r_a[ks][j0] = a0 + a1; r_c[ks][j0] = c0 + c1;
    __syncthreads();
    if (ks == 0) {
        const float A = r_a[0][j0] + r_a[1][j0] + r_a[2][j0] + r_a[3][j0];
        const float C = r_c[0][j0] + r_c[1][j0] + r_c[2][j0] + r_c[3][j0];
        const float g = 1.f / (1.f + expf(-(A + C)));
        float o2 = g * s_o1[j] + (1.f - g) * s_typ[j];
        if (estar < 0) o2 = emb_table[(size_t)tok * Hn + j];  // mask row never updated
        me_t[j * Bn + b] = o2;
    }
}

// ---------------- LM head: out[b][v] = sum_k me_t[k][b]*lm_W[k][v] + lm_b[v]
// 393 blocks x 512 threads; 8 waves split K (96 each) over the block's 128 v's.
// me_t staged in LDS once (ds_read/lgkmcnt) so the ONLY vmcnt stream is the
// double-buffered 8-deep lm_W prefetch -> counted vmcnt waits, misses stay in
// flight. smem reused for the cross-wave reduction after a barrier.
__global__ __launch_bounds__(512, 2) void lm_head(
    const float* __restrict__ me_t, const float* __restrict__ lm_W,
    const float* __restrict__ lm_b, float* __restrict__ out)
{
    __shared__ __align__(16) float smem[WPB * Bn * VPB];   // 64 KB (me stage, then red)

    const int tid  = threadIdx.x;
    const int lane = tid & 63;
    const int w    = tid >> 6;                        // 0..7
    const int v0   = blockIdx.x * VPB + lane * 2;     // two consecutive v's

    // ---- stage me_t (Hn*Bn = 12288 floats = 48 KB) into LDS, coalesced
    {
        const float4* __restrict__ src = (const float4*)me_t;
        float4* __restrict__ dst = (float4*)smem;
        #pragma unroll
        for (int i = 0; i < (Hn * Bn / 4) / 512; ++i)   // 6 float4 per thread
            dst[i * 512 + tid] = src[i * 512 + tid];
    }
    __syncthreads();

    const int kb = w * KPW;
    float2 acc[Bn];
    #pragma unroll
    for (int i = 0; i < Bn; ++i) acc[i] = make_float2(0.f, 0.f);

    const float4* __restrict__ mp = (const float4*)smem + kb * 4;  // LDS, broadcast

    if (v0 + 1 < Vn) {
        // ---- fast path: pure lm_W vmcnt stream, register double-buffer
        const float* __restrict__ wp = lm_W + (size_t)kb * Vn + v0;
        float2 cur[CH], nxt[CH];
        #pragma unroll
        for (int u = 0; u < CH; ++u)
            cur[u] = *(const float2*)(wp + (size_t)u * Vn);

        for (int k0 = 0; k0 < KPW; k0 += CH) {
            if (k0 + CH < KPW) {
                #pragma unroll
                for (int u = 0; u < CH; ++u)
                    nxt[u] = *(const float2*)(wp + (size_t)(k0 + CH + u) * Vn);
            }
            #pragma unroll
            for (int u = 0; u < CH; ++u) {
                const float2 wv = cur[u];
                const float4 m0 = mp[(k0 + u) * 4 + 0];   // ds_read_b128 broadcast
                const float4 m1 = mp[(k0 + u) * 4 + 1];
                const float4 m2 = mp[(k0 + u) * 4 + 2];
                const float4 m3 = mp[(k0 + u) * 4 + 3];
#define FMA8(q, mq)                                                          \
                acc[q*4+0].x = fmaf(mq.x, wv.x, acc[q*4+0].x);               \
                acc[q*4+0].y = fmaf(mq.x, wv.y, acc[q*4+0].y);               \
                acc[q*4+1].x = fmaf(mq.y, wv.x, acc[q*4+1].x);               \
                acc[q*4+1].y = fmaf(mq.y, wv.y, acc[q*4+1].y);               \
                acc[q*4+2].x = fmaf(mq.z, wv.x, acc[q*4+2].x);               \
                acc[q*4+2].y = fmaf(mq.z, wv.y, acc[q*4+2].y);               \
                acc[q*4+3].x = fmaf(mq.w, wv.x, acc[q*4+3].x);               \
                acc[q*4+3].y = fmaf(mq.w, wv.y, acc[q*4+3].y);
                FMA8(0, m0) FMA8(1, m1) FMA8(2, m2) FMA8(3, m3)
#undef FMA8
            }
            #pragma unroll
            for (int u = 0; u < CH; ++u) cur[u] = nxt[u];
        }
    } else {
        // ---- tail path (last block only): at most one valid v (v0 == Vn-1)
        const int vx = (v0 < Vn) ? v0 : (Vn - 1);     // OOB lanes: dummy, never read
        const float* __restrict__ wq = lm_W + (size_t)kb * Vn + vx;
        for (int k = 0; k < KPW; ++k) {
            const float wvx = wq[(size_t)k * Vn];
            const float4 m0 = mp[k * 4 + 0];
            const float4 m1 = mp[k * 4 + 1];
            const float4 m2 = mp[k * 4 + 2];
            const float4 m3 = mp[k * 4 + 3];
            acc[0].x  = fmaf(m0.x, wvx, acc[0].x);
            acc[1].x  = fmaf(m0.y, wvx, acc[1].x);
            acc[2].x  = fmaf(m0.z, wvx, acc[2].x);
            acc[3].x  = fmaf(m0.w, wvx, acc[3].x);
            acc[4].x  = fmaf(m1.x, wvx, acc[4].x);
            acc[5].x  = fmaf(m1.y, wvx, acc[5].x);
            acc[6].x  = fmaf(m1.z, wvx, acc[6].x);
            acc[7].x  = fmaf(m1.w, wvx, acc[7].x);
            acc[8].x  = fmaf(m2.x, wvx, acc[8].x);
            acc[9].x  = fmaf(m2.y, wvx, acc[9].x);
            acc[10].x = fmaf(m2.z, wvx, acc[10].x);
            acc[11].x = fmaf(m2.w, wvx, acc[11].x);
            acc[12].x = fmaf(m3.x, wvx, acc[12].x);
            acc[13].x = fmaf(m3.y, wvx, acc[13].x);
            acc[14].x = fmaf(m3.z, wvx, acc[14].x);
            acc[15].x = fmaf(m3.w, wvx, acc[15].x);
        }
    }

    __syncthreads();                                  // all me reads done; reuse smem
    #pragma unroll
    for (int b = 0; b < Bn; ++b)
        *(float2*)&smem[(w * Bn + b) * VPB + lane * 2] = acc[b];
    __syncthreads();

    #pragma unroll
    for (int p0 = 0; p0 < 4; ++p0) {
        const int p  = p0 * 512 + tid;                // 0..2047 = 16 b x 128 v
        const int b  = p >> 7;
        const int l  = p & 127;
        const int vv = blockIdx.x * VPB + l;
        if (vv < Vn) {
            float s = 0.f;
            #pragma unroll
            for (int ww = 0; ww < WPB; ++ww) s += smem[(ww * Bn + b) * VPB + l];
            out[(size_t)b * Vn + vv] = s + lm_b[vv];
        }
    }
}

extern "C" void kernel_launch(void* const* d_in, const int* in_sizes, int n_in,
                              void* d_out, int out_size, void* d_ws, size_t ws_size,
                              hipStream_t stream) {
    const int*   batch_arg    = (const int*)  d_in[0];
    const int*   event_pos    = (const int*)  d_in[1];
    const int*   mask_indices = (const int*)  d_in[2];
    const float* sent_emb     = (const float*)d_in[3];
    const float* type_emb     = (const float*)d_in[4];
    const float* emb_table    = (const float*)d_in[5];
    const float* W1_1         = (const float*)d_in[6];
    const float* W1_2         = (const float*)d_in[7];
    const float* W2_1         = (const float*)d_in[8];
    const float* W2_2         = (const float*)d_in[9];
    const float* lm_W         = (const float*)d_in[10];
    const float* lm_b         = (const float*)d_in[11];
    float* out = (float*)d_out;

    float* o1_ws = (float*)d_ws;                 // Bn*Hn floats
    float* me_t  = o1_ws + (size_t)Bn * Hn;      // Hn*Bn floats (16B aligned)

    dim3 g12(Bn, Hn / 64);
    gate_layer1<<<g12, 256, 0, stream>>>(batch_arg, event_pos, mask_indices,
                                         sent_emb, emb_table, W1_1, W1_2, o1_ws);
    gate_layer2<<<g12, 256, 0, stream>>>(batch_arg, event_pos, mask_indices,
                                         type_emb, emb_table, W2_1, W2_2, o1_ws, me_t);

    lm_head<<<(Vn + VPB - 1) / VPB, 512, 0, stream>>>(me_t, lm_W, lm_b, out);
}

// Round 8
// 65.965 us; speedup vs baseline: 1.8410x; 1.0215x over previous
//
#include <hip/hip_runtime.h>

#define Hn 768
#define Bn 16
#define Sn 512
#define En 32
#define Vn 50265

#define WPB 8           // waves per lm_head block
#define KPW (Hn / WPB)  // 96 k per wave
#define VPB 128         // v per lm_head block
#define CH  4           // wv prefetch depth (k's per chunk, float4 each)

// ---------------- Layer 1: o1 = g1*inst + (1-g1)*sent, g1 = sigmoid(inst@W1_1 + sent@W1_2)
__global__ __launch_bounds__(256) void gate_layer1(
    const int* __restrict__ batch_arg, const int* __restrict__ event_pos,
    const int* __restrict__ mask_indices, const float* __restrict__ sent_emb,
    const float* __restrict__ emb_table, const float* __restrict__ W1_1,
    const float* __restrict__ W1_2, float* __restrict__ o1_out)
{
    const int b  = blockIdx.x;
    const int j0 = threadIdx.x & 63;
    const int ks = threadIdx.x >> 6;           // wave-uniform
    const int j  = blockIdx.y * 64 + j0;

    const int mask = mask_indices[b];
    int estar = -1;
    #pragma unroll
    for (int e = 0; e < En; ++e)
        if (event_pos[b * En + e] == mask && estar < 0) estar = e;
    const int tok = batch_arg[b * Sn + mask];

    __shared__ __align__(16) float s_inst[Hn];
    __shared__ __align__(16) float s_sent[Hn];
    for (int t = threadIdx.x; t < Hn; t += 256) {
        s_inst[t] = emb_table[(size_t)tok * Hn + t];
        s_sent[t] = (estar >= 0) ? sent_emb[((size_t)b * En + estar) * Hn + t] : 0.f;
    }
    __syncthreads();

    float a0 = 0.f, a1 = 0.f, c0 = 0.f, c1 = 0.f;
    const float* __restrict__ w1 = W1_1 + (size_t)ks * 192 * Hn + j;
    const float* __restrict__ w2 = W1_2 + (size_t)ks * 192 * Hn + j;
    const float4* __restrict__ si = (const float4*)(s_inst + ks * 192);
    const float4* __restrict__ ss = (const float4*)(s_sent + ks * 192);
    #pragma unroll 4
    for (int k4 = 0; k4 < 48; ++k4) {
        const float4 iv = si[k4];
        const float4 sv = ss[k4];
        const float* __restrict__ wa = w1 + (size_t)k4 * 4 * Hn;
        const float* __restrict__ wb = w2 + (size_t)k4 * 4 * Hn;
        a0 = fmaf(iv.x, wa[0],      a0);
        a1 = fmaf(iv.y, wa[Hn],     a1);
        a0 = fmaf(iv.z, wa[2 * Hn], a0);
        a1 = fmaf(iv.w, wa[3 * Hn], a1);
        c0 = fmaf(sv.x, wb[0],      c0);
        c1 = fmaf(sv.y, wb[Hn],     c1);
        c0 = fmaf(sv.z, wb[2 * Hn], c0);
        c1 = fmaf(sv.w, wb[3 * Hn], c1);
    }

    __shared__ float r_a[4][64];
    __shared__ float r_c[4][64];
    r_a[ks][j0] = a0 + a1; r_c[ks][j0] = c0 + c1;
    __syncthreads();
    if (ks == 0) {
        const float A = r_a[0][j0] + r_a[1][j0] + r_a[2][j0] + r_a[3][j0];
        const float C = r_c[0][j0] + r_c[1][j0] + r_c[2][j0] + r_c[3][j0];
        const float g = 1.f / (1.f + expf(-(A + C)));
        o1_out[b * Hn + j] = g * s_inst[j] + (1.f - g) * s_sent[j];
    }
}

// ---------------- Layer 2: o2 = g2*o1 + (1-g2)*typ, written TRANSPOSED as me_t[k][b]
__global__ __launch_bounds__(256) void gate_layer2(
    const int* __restrict__ batch_arg, const int* __restrict__ event_pos,
    const int* __restrict__ mask_indices, const float* __restrict__ type_emb,
    const float* __restrict__ emb_table, const float* __restrict__ W2_1,
    const float* __restrict__ W2_2, const float* __restrict__ o1_in,
    float* __restrict__ me_t)
{
    const int b  = blockIdx.x;
    const int j0 = threadIdx.x & 63;
    const int ks = threadIdx.x >> 6;
    const int j  = blockIdx.y * 64 + j0;

    const int mask = mask_indices[b];
    int estar = -1;
    #pragma unroll
    for (int e = 0; e < En; ++e)
        if (event_pos[b * En + e] == mask && estar < 0) estar = e;
    const int tok = batch_arg[b * Sn + mask];

    __shared__ __align__(16) float s_o1[Hn];
    __shared__ __align__(16) float s_typ[Hn];
    for (int t = threadIdx.x; t < Hn; t += 256) {
        s_o1[t]  = o1_in[b * Hn + t];
        s_typ[t] = type_emb[((size_t)b * Sn + mask) * Hn + t];
    }
    __syncthreads();

    float a0 = 0.f, a1 = 0.f, c0 = 0.f, c1 = 0.f;
    const float* __restrict__ w1 = W2_1 + (size_t)ks * 192 * Hn + j;
    const float* __restrict__ w2 = W2_2 + (size_t)ks * 192 * Hn + j;
    const float4* __restrict__ so = (const float4*)(s_o1  + ks * 192);
    const float4* __restrict__ st = (const float4*)(s_typ + ks * 192);
    #pragma unroll 4
    for (int k4 = 0; k4 < 48; ++k4) {
        const float4 ov = so[k4];
        const float4 tv = st[k4];
        const float* __restrict__ wa = w1 + (size_t)k4 * 4 * Hn;
        const float* __restrict__ wb = w2 + (size_t)k4 * 4 * Hn;
        a0 = fmaf(ov.x, wa[0],      a0);
        a1 = fmaf(ov.y, wa[Hn],     a1);
        a0 = fmaf(ov.z, wa[2 * Hn], a0);
        a1 = fmaf(ov.w, wa[3 * Hn], a1);
        c0 = fmaf(tv.x, wb[0],      c0);
        c1 = fmaf(tv.y, wb[Hn],     c1);
        c0 = fmaf(tv.z, wb[2 * Hn], c0);
        c1 = fmaf(tv.w, wb[3 * Hn], c1);
    }

    __shared__ float r_a[4][64];
    __shared__ float r_c[4][64];
    r_a[ks][j0] = a0 + a1; r_c[ks][j0] = c0 + c1;
    __syncthreads();
    if (ks == 0) {
        const float A = r_a[0][j0] + r_a[1][j0] + r_a[2][j0] + r_a[3][j0];
        const float C = r_c[0][j0] + r_c[1][j0] + r_c[2][j0] + r_c[3][j0];
        const float g = 1.f / (1.f + expf(-(A + C)));
        float o2 = g * s_o1[j] + (1.f - g) * s_typ[j];
        if (estar < 0) o2 = emb_table[(size_t)tok * Hn + j];  // mask row never updated
        me_t[j * Bn + b] = o2;
    }
}

// ---------------- LM head: out[b][v] = sum_k me_t[k][b]*lm_W[k][v] + lm_b[v]
// 393 blocks x 512 threads. Thread = 4 v (float4 W) x 8 b (lane parity picks
// the b-half) -> per k: 2 ds_read_b128 (halved LDS pressure) + 1 float4 W load
// + 32 fmaf. me_t staged in LDS (lgkmcnt stream); W register double-buffered
// (pure vmcnt stream, counted waits). smem reused for cross-wave reduction.
__global__ __launch_bounds__(512, 2) void lm_head(
    const float* __restrict__ me_t, const float* __restrict__ lm_W,
    const float* __restrict__ lm_b, float* __restrict__ out)
{
    __shared__ __align__(16) float smem[WPB * Bn * VPB];   // 64 KB (me stage, then red)

    const int tid  = threadIdx.x;
    const int lane = tid & 63;
    const int w    = tid >> 6;                    // 0..7
    const int bh   = lane & 1;                    // b-half: 0 -> b0-7, 1 -> b8-15
    const int vq   = lane >> 1;                   // 0..31
    const int v0   = blockIdx.x * VPB + vq * 4;   // four consecutive v's

    // ---- stage me_t (Hn*Bn = 12288 floats = 48 KB) into LDS, coalesced
    {
        const float4* __restrict__ src = (const float4*)me_t;
        float4* __restrict__ dst = (float4*)smem;
        #pragma unroll
        for (int i = 0; i < 6; ++i)
            dst[i * 512 + tid] = src[i * 512 + tid];
    }
    __syncthreads();

    const int kb = w * KPW;
    float4 acc[8];
    #pragma unroll
    for (int i = 0; i < 8; ++i) acc[i] = make_float4(0.f, 0.f, 0.f, 0.f);

    const float* __restrict__ mb = smem + kb * Bn + bh * 8;   // me[k][bh*8 + ...]

#define FMA32(wv, m0, m1)                                                     \
    acc[0].x = fmaf(m0.x, wv.x, acc[0].x); acc[0].y = fmaf(m0.x, wv.y, acc[0].y); \
    acc[0].z = fmaf(m0.x, wv.z, acc[0].z); acc[0].w = fmaf(m0.x, wv.w, acc[0].w); \
    acc[1].x = fmaf(m0.y, wv.x, acc[1].x); acc[1].y = fmaf(m0.y, wv.y, acc[1].y); \
    acc[1].z = fmaf(m0.y, wv.z, acc[1].z); acc[1].w = fmaf(m0.y, wv.w, acc[1].w); \
    acc[2].x = fmaf(m0.z, wv.x, acc[2].x); acc[2].y = fmaf(m0.z, wv.y, acc[2].y); \
    acc[2].z = fmaf(m0.z, wv.z, acc[2].z); acc[2].w = fmaf(m0.z, wv.w, acc[2].w); \
    acc[3].x = fmaf(m0.w, wv.x, acc[3].x); acc[3].y = fmaf(m0.w, wv.y, acc[3].y); \
    acc[3].z = fmaf(m0.w, wv.z, acc[3].z); acc[3].w = fmaf(m0.w, wv.w, acc[3].w); \
    acc[4].x = fmaf(m1.x, wv.x, acc[4].x); acc[4].y = fmaf(m1.x, wv.y, acc[4].y); \
    acc[4].z = fmaf(m1.x, wv.z, acc[4].z); acc[4].w = fmaf(m1.x, wv.w, acc[4].w); \
    acc[5].x = fmaf(m1.y, wv.x, acc[5].x); acc[5].y = fmaf(m1.y, wv.y, acc[5].y); \
    acc[5].z = fmaf(m1.y, wv.z, acc[5].z); acc[5].w = fmaf(m1.y, wv.w, acc[5].w); \
    acc[6].x = fmaf(m1.z, wv.x, acc[6].x); acc[6].y = fmaf(m1.z, wv.y, acc[6].y); \
    acc[6].z = fmaf(m1.z, wv.z, acc[6].z); acc[6].w = fmaf(m1.z, wv.w, acc[6].w); \
    acc[7].x = fmaf(m1.w, wv.x, acc[7].x); acc[7].y = fmaf(m1.w, wv.y, acc[7].y); \
    acc[7].z = fmaf(m1.w, wv.z, acc[7].z); acc[7].w = fmaf(m1.w, wv.w, acc[7].w);

    if (__all(v0 + 3 < Vn)) {
        // ---- fast path: pure lm_W vmcnt stream, register double-buffer
        const float* __restrict__ wp = lm_W + (size_t)kb * Vn + v0;
        float4 cur[CH], nxt[CH];
        #pragma unroll
        for (int u = 0; u < CH; ++u)
            cur[u] = *(const float4*)(wp + (size_t)u * Vn);

        for (int k0 = 0; k0 < KPW; k0 += CH) {
            if (k0 + CH < KPW) {
                #pragma unroll
                for (int u = 0; u < CH; ++u)
                    nxt[u] = *(const float4*)(wp + (size_t)(k0 + CH + u) * Vn);
            }
            #pragma unroll
            for (int u = 0; u < CH; ++u) {
                const float4 wv = cur[u];
                const float4 m0 = *(const float4*)(mb + (k0 + u) * Bn);      // ds_read_b128
                const float4 m1 = *(const float4*)(mb + (k0 + u) * Bn + 4);  // ds_read_b128
                FMA32(wv, m0, m1)
            }
            #pragma unroll
            for (int u = 0; u < CH; ++u) cur[u] = nxt[u];
        }
    } else {
        // ---- tail path (wave-uniform; last block only): clamped scalar loads.
        // acc for duplicated/OOB v's lands in red slots never read back.
        const float* __restrict__ wq = lm_W + (size_t)kb * Vn;
        const int vx0 = (v0     < Vn) ? v0     : (Vn - 1);
        const int vx1 = (v0 + 1 < Vn) ? v0 + 1 : (Vn - 1);
        const int vx2 = (v0 + 2 < Vn) ? v0 + 2 : (Vn - 1);
        const int vx3 = (v0 + 3 < Vn) ? v0 + 3 : (Vn - 1);
        for (int k = 0; k < KPW; ++k) {
            float4 wv;
            wv.x = wq[(size_t)k * Vn + vx0];
            wv.y = wq[(size_t)k * Vn + vx1];
            wv.z = wq[(size_t)k * Vn + vx2];
            wv.w = wq[(size_t)k * Vn + vx3];
            const float4 m0 = *(const float4*)(mb + k * Bn);
            const float4 m1 = *(const float4*)(mb + k * Bn + 4);
            FMA32(wv, m0, m1)
        }
    }
#undef FMA32

    __syncthreads();                              // all me reads done; reuse smem
    #pragma unroll
    for (int i = 0; i < 8; ++i)
        *(float4*)&smem[((w * Bn) + bh * 8 + i) * VPB + vq * 4] = acc[i];
    __syncthreads();

    #pragma unroll
    for (int p0 = 0; p0 < 4; ++p0) {
        const int p  = p0 * 512 + tid;            // 0..2047 = 16 b x 128 v
        const int b  = p >> 7;
        const int l  = p & 127;
        const int vv = blockIdx.x * VPB + l;
        if (vv < Vn) {
            float s = 0.f;
            #pragma unroll
            for (int ww = 0; ww < WPB; ++ww) s += smem[(ww * Bn + b) * VPB + l];
            out[(size_t)b * Vn + vv] = s + lm_b[vv];
        }
    }
}

extern "C" void kernel_launch(void* const* d_in, const int* in_sizes, int n_in,
                              void* d_out, int out_size, void* d_ws, size_t ws_size,
                              hipStream_t stream) {
    const int*   batch_arg    = (const int*)  d_in[0];
    const int*   event_pos    = (const int*)  d_in[1];
    const int*   mask_indices = (const int*)  d_in[2];
    const float* sent_emb     = (const float*)d_in[3];
    const float* type_emb     = (const float*)d_in[4];
    const float* emb_table    = (const float*)d_in[5];
    const float* W1_1         = (const float*)d_in[6];
    const float* W1_2         = (const float*)d_in[7];
    const float* W2_1         = (const float*)d_in[8];
    const float* W2_2         = (const float*)d_in[9];
    const float* lm_W         = (const float*)d_in[10];
    const float* lm_b         = (const float*)d_in[11];
    float* out = (float*)d_out;

    float* o1_ws = (float*)d_ws;                 // Bn*Hn floats
    float* me_t  = o1_ws + (size_t)Bn * Hn;      // Hn*Bn floats (16B aligned)

    dim3 g12(Bn, Hn / 64);
    gate_layer1<<<g12, 256, 0, stream>>>(batch_arg, event_pos, mask_indices,
                                         sent_emb, emb_table, W1_1, W1_2, o1_ws);
    gate_layer2<<<g12, 256, 0, stream>>>(batch_arg, event_pos, mask_indices,
                                         type_emb, emb_table, W2_1, W2_2, o1_ws, me_t);

    lm_head<<<(Vn + VPB - 1) / VPB, 512, 0, stream>>>(me_t, lm_W, lm_b, out);
}